// Round 2
// baseline (48.440 us; speedup 1.0000x reference)
//
#include <hip/hip_runtime.h>

#define NCH 14
#define TR 512                    // tile rows
#define TF (TR * NCH)             // 7168 floats per operand tile
#define TF4 (TF / 4)              // 1792 float4
#define BT 256                    // block threads
#define F4T (TF4 / BT)            // 7 float4 loads per thread per operand

__device__ __forceinline__ float row_loss14(const float* xs, const float* ts, unsigned pack) {
    // gb bit g set iff any target in group g is > 0 (constant-indexed, stays in VGPRs)
    unsigned gb = 0u;
#pragma unroll
    for (int c = 0; c < NCH; ++c) {
        int gc = (pack >> (2 * c)) & 3;
        gb |= (ts[c] > 0.0f) ? (1u << gc) : 0u;
    }
    float acc = 0.0f;
#pragma unroll
    for (int c = 0; c < NCH; ++c) {
        int gc = (pack >> (2 * c)) & 3;
        float xv = xs[c], tv = ts[c];
        float bce = fmaxf(xv, 0.0f) - xv * tv + __logf(1.0f + __expf(-fabsf(xv)));
        bool keep = (gc == 0) || ((gb >> gc) & 1u);
        acc += keep ? bce : 0.0f;
    }
    return acc;
}

__global__ __launch_bounds__(BT) void bce_partial(
    const float* __restrict__ x, const float* __restrict__ t,
    const int* __restrict__ groups, float* __restrict__ partial, int rows)
{
    __shared__ float sx[TF];
    __shared__ float st[TF];

    unsigned pack = 0u;
#pragma unroll
    for (int c = 0; c < NCH; ++c) pack |= ((unsigned)(groups[c] & 3)) << (2 * c);

    const int tid = threadIdx.x;
    const int ntiles = (rows + TR - 1) / TR;
    float acc = 0.0f;

    for (int tile = blockIdx.x; tile < ntiles; tile += gridDim.x) {
        const size_t base = (size_t)tile * TF;
        const int tile_rows = min(TR, rows - tile * TR);
        const int tile_floats = tile_rows * NCH;

        __syncthreads();  // previous tile's compute done before LDS overwrite

        if (tile_floats == TF) {
            // Fast path: fully coalesced float4 staging (lane i -> float4 i).
            const float4* xg = (const float4*)(x + base);
            const float4* tg = (const float4*)(t + base);
            float4 xr[F4T], tr[F4T];
#pragma unroll
            for (int k = 0; k < F4T; ++k) {
                xr[k] = xg[k * BT + tid];
                tr[k] = tg[k * BT + tid];
            }
            float4* sxv = (float4*)sx;
            float4* stv = (float4*)st;
#pragma unroll
            for (int k = 0; k < F4T; ++k) {
                sxv[k * BT + tid] = xr[k];
                stv[k * BT + tid] = tr[k];
            }
        } else {
            // Tail tile: scalar guarded staging (runs once).
            for (int i = tid; i < tile_floats; i += BT) {
                sx[i] = x[base + i];
                st[i] = t[base + i];
            }
        }
        __syncthreads();

        // Each thread consumes 2 rows = 28 contiguous floats = 7 float4 LDS
        // reads; stride 112 B -> each 8-lane octet covers all 32 banks once
        // (balanced, conflict-free in throughput terms).
        const int r0 = 2 * tid;
        if (r0 < tile_rows) {
            const float4* v = (const float4*)(sx + (size_t)tid * 2 * NCH);
            const float4* w = (const float4*)(st + (size_t)tid * 2 * NCH);
            float xs[2 * NCH], ts[2 * NCH];
#pragma unroll
            for (int j = 0; j < 7; ++j) {
                float4 a = v[j], b = w[j];
                xs[4 * j + 0] = a.x; xs[4 * j + 1] = a.y; xs[4 * j + 2] = a.z; xs[4 * j + 3] = a.w;
                ts[4 * j + 0] = b.x; ts[4 * j + 1] = b.y; ts[4 * j + 2] = b.z; ts[4 * j + 3] = b.w;
            }
            acc += row_loss14(xs, ts, pack);
            if (r0 + 1 < tile_rows) acc += row_loss14(xs + NCH, ts + NCH, pack);
        }
    }

    // Wave (64-lane) reduction, then block reduction.
#pragma unroll
    for (int off = 32; off > 0; off >>= 1) acc += __shfl_xor(acc, off);

    __shared__ float wsum[BT / 64];
    const int lane = tid & 63;
    const int wid = tid >> 6;
    if (lane == 0) wsum[wid] = acc;
    __syncthreads();
    if (tid == 0)
        partial[blockIdx.x] = wsum[0] + wsum[1] + wsum[2] + wsum[3];
}

__global__ __launch_bounds__(256) void finalize(
    const float* __restrict__ partial, int n, float* __restrict__ out, double inv_count)
{
    double s = 0.0;
    for (int i = threadIdx.x; i < n; i += 256) s += (double)partial[i];

    __shared__ double sd[256];
    sd[threadIdx.x] = s;
    __syncthreads();
#pragma unroll
    for (int step = 128; step > 0; step >>= 1) {
        if (threadIdx.x < step) sd[threadIdx.x] += sd[threadIdx.x + step];
        __syncthreads();
    }
    if (threadIdx.x == 0) out[0] = (float)(sd[0] * inv_count);
}

extern "C" void kernel_launch(void* const* d_in, const int* in_sizes, int n_in,
                              void* d_out, int out_size, void* d_ws, size_t ws_size,
                              hipStream_t stream) {
    const float* x = (const float*)d_in[0];
    const float* t = (const float*)d_in[1];
    const int* groups = (const int*)d_in[2];
    float* out = (float*)d_out;
    float* partial = (float*)d_ws;

    const int total = in_sizes[0];
    const int rows = total / NCH;
    const int ntiles = (rows + TR - 1) / TR;

    int blocks = ntiles;
    if (blocks > 8192) blocks = 8192;
    if ((size_t)blocks * sizeof(float) > ws_size)
        blocks = (int)(ws_size / sizeof(float));
    if (blocks < 1) blocks = 1;

    bce_partial<<<blocks, BT, 0, stream>>>(x, t, groups, partial, rows);

    const double inv_count = 1.0 / ((double)rows * (double)NCH);
    finalize<<<1, 256, 0, stream>>>(partial, blocks, out, inv_count);
}

// Round 3
// 44.936 us; speedup vs baseline: 1.0780x; 1.0780x over previous
//
#include <hip/hip_runtime.h>

#define NCH 14
#define BT 256
#define LN2F 0.69314718055994530942f

// setup_inputs() group map: {0,1,1,2,2,0,3,3,1,2,0,3,1,2}
#define EXPECTED_PACK ((0u<<0)|(1u<<2)|(1u<<4)|(2u<<6)|(2u<<8)|(0u<<10)|(3u<<12)|(3u<<14)| \
                       (1u<<16)|(2u<<18)|(0u<<20)|(3u<<22)|(1u<<24)|(2u<<26))

__device__ __forceinline__ unsigned make_pack(const int* __restrict__ groups) {
    unsigned p = 0u;
#pragma unroll
    for (int c = 0; c < NCH; ++c) p |= ((unsigned)(groups[c] & 3)) << (2 * c);
    return p;
}

// Specialized: groups known at compile time -> per-row group sums, 3 compares,
// 6 selects; log term kept in log2 units (ln2 multiply deferred to the end).
__device__ __forceinline__ void row_spec(const float* xs, const float* ts,
                                         float& accL, float& accG) {
    float lin[NCH], lg[NCH];
#pragma unroll
    for (int c = 0; c < NCH; ++c) {
        float xv = xs[c];
        lin[c] = fmaf(-xv, ts[c], fmaxf(xv, 0.0f));
        float z = __expf(-fabsf(xv));
        lg[c] = __log2f(1.0f + z);
    }
    // group membership (compile-time): g0={0,5,10} g1={1,2,8,12} g2={3,4,9,13} g3={6,7,11}
    float s1 = ts[1] + ts[2] + ts[8] + ts[12];
    float s2 = ts[3] + ts[4] + ts[9] + ts[13];
    float s3 = ts[6] + ts[7] + ts[11];

    float rL0 = lin[0] + lin[5] + lin[10],            rG0 = lg[0] + lg[5] + lg[10];
    float rL1 = lin[1] + lin[2] + lin[8] + lin[12],   rG1 = lg[1] + lg[2] + lg[8] + lg[12];
    float rL2 = lin[3] + lin[4] + lin[9] + lin[13],   rG2 = lg[3] + lg[4] + lg[9] + lg[13];
    float rL3 = lin[6] + lin[7] + lin[11],            rG3 = lg[6] + lg[7] + lg[11];

    accL += rL0;                        accG += rG0;
    accL += (s1 > 0.0f) ? rL1 : 0.0f;   accG += (s1 > 0.0f) ? rG1 : 0.0f;
    accL += (s2 > 0.0f) ? rL2 : 0.0f;   accG += (s2 > 0.0f) ? rG2 : 0.0f;
    accL += (s3 > 0.0f) ? rL3 : 0.0f;   accG += (s3 > 0.0f) ? rG3 : 0.0f;
}

// Generic fallback: runtime groups via 2-bit pack (correct for any groups).
__device__ __forceinline__ void row_gen(const float* xs, const float* ts,
                                        unsigned pack, float& accL, float& accG) {
    unsigned gb = 0u;
#pragma unroll
    for (int c = 0; c < NCH; ++c) {
        int gc = (pack >> (2 * c)) & 3;
        gb |= (ts[c] > 0.0f) ? (1u << gc) : 0u;
    }
#pragma unroll
    for (int c = 0; c < NCH; ++c) {
        int gc = (pack >> (2 * c)) & 3;
        float xv = xs[c];
        float lin = fmaf(-xv, ts[c], fmaxf(xv, 0.0f));
        float lg = __log2f(1.0f + __expf(-fabsf(xv)));
        bool keep = (gc == 0) || ((gb >> gc) & 1u);
        accL += keep ? lin : 0.0f;
        accG += keep ? lg : 0.0f;
    }
}

__global__ __launch_bounds__(BT) void bce_partial(
    const float* __restrict__ x, const float* __restrict__ t,
    const int* __restrict__ groups, float* __restrict__ partial,
    int rows, int iters)
{
    const unsigned pack = make_pack(groups);
    const bool spec = (pack == EXPECTED_PACK);
    const int pairs = rows >> 1;
    const int nth = gridDim.x * BT;

    float accL = 0.0f, accG = 0.0f;

    for (int it = 0; it < iters; ++it) {
        const int p = blockIdx.x * BT + threadIdx.x + it * nth;
        if (p < pairs) {
            const float4* xp = (const float4*)(x + (size_t)p * (2 * NCH));
            const float4* tp = (const float4*)(t + (size_t)p * (2 * NCH));
            float xs[2 * NCH], ts[2 * NCH];
#pragma unroll
            for (int j = 0; j < 7; ++j) {
                float4 a = xp[j];
                float4 b = tp[j];
                xs[4 * j + 0] = a.x; xs[4 * j + 1] = a.y; xs[4 * j + 2] = a.z; xs[4 * j + 3] = a.w;
                ts[4 * j + 0] = b.x; ts[4 * j + 1] = b.y; ts[4 * j + 2] = b.z; ts[4 * j + 3] = b.w;
            }
            if (spec) {
                row_spec(xs, ts, accL, accG);
                row_spec(xs + NCH, ts + NCH, accL, accG);
            } else {
                row_gen(xs, ts, pack, accL, accG);
                row_gen(xs + NCH, ts + NCH, pack, accL, accG);
            }
        }
    }

    // Odd-row tail (rows=2e6 -> not taken; kept for generality).
    if ((rows & 1) && blockIdx.x == 0 && threadIdx.x == 0) {
        const size_t base = (size_t)(rows - 1) * NCH;
        float xs[NCH], ts[NCH];
#pragma unroll
        for (int c = 0; c < NCH; ++c) { xs[c] = x[base + c]; ts[c] = t[base + c]; }
        row_gen(xs, ts, pack, accL, accG);
    }

    float acc = fmaf(LN2F, accG, accL);

    // 64-lane wave reduction, then block reduction.
#pragma unroll
    for (int off = 32; off > 0; off >>= 1) acc += __shfl_xor(acc, off);

    __shared__ float wsum[BT / 64];
    const int lane = threadIdx.x & 63;
    const int wid = threadIdx.x >> 6;
    if (lane == 0) wsum[wid] = acc;
    __syncthreads();
    if (threadIdx.x == 0)
        partial[blockIdx.x] = wsum[0] + wsum[1] + wsum[2] + wsum[3];
}

__global__ __launch_bounds__(256) void finalize(
    const float* __restrict__ partial, int n, float* __restrict__ out, double inv_count)
{
    double s = 0.0;
    for (int i = threadIdx.x; i < n; i += 256) s += (double)partial[i];

    __shared__ double sd[256];
    sd[threadIdx.x] = s;
    __syncthreads();
#pragma unroll
    for (int step = 128; step > 0; step >>= 1) {
        if (threadIdx.x < step) sd[threadIdx.x] += sd[threadIdx.x + step];
        __syncthreads();
    }
    if (threadIdx.x == 0) out[0] = (float)(sd[0] * inv_count);
}

extern "C" void kernel_launch(void* const* d_in, const int* in_sizes, int n_in,
                              void* d_out, int out_size, void* d_ws, size_t ws_size,
                              hipStream_t stream) {
    const float* x = (const float*)d_in[0];
    const float* t = (const float*)d_in[1];
    const int* groups = (const int*)d_in[2];
    float* out = (float*)d_out;
    float* partial = (float*)d_ws;

    const int total = in_sizes[0];
    const int rows = total / NCH;
    const int pairs = rows >> 1;

    int blocks = (pairs + BT - 1) / BT;            // exact grid: 1 pair / thread
    if ((size_t)blocks * sizeof(float) > ws_size)
        blocks = (int)(ws_size / sizeof(float));   // ws-limited fallback
    if (blocks < 1) blocks = 1;
    const int iters = (pairs + blocks * BT - 1) / (blocks * BT);

    bce_partial<<<blocks, BT, 0, stream>>>(x, t, groups, partial, rows, iters);

    const double inv_count = 1.0 / ((double)rows * (double)NCH);
    finalize<<<1, 256, 0, stream>>>(partial, blocks, out, inv_count);
}

// Round 4
// 42.989 us; speedup vs baseline: 1.1268x; 1.0453x over previous
//
#include <hip/hip_runtime.h>

#define NCH 14
#define BT 256
#define NBLOCKS 512
#define LN2F 0.69314718055994530942f

// setup_inputs() group map: {0,1,1,2,2,0,3,3,1,2,0,3,1,2}
#define EXPECTED_PACK ((0u<<0)|(1u<<2)|(1u<<4)|(2u<<6)|(2u<<8)|(0u<<10)|(3u<<12)|(3u<<14)| \
                       (1u<<16)|(2u<<18)|(0u<<20)|(3u<<22)|(1u<<24)|(2u<<26))

__device__ __forceinline__ unsigned make_pack(const int* __restrict__ groups) {
    unsigned p = 0u;
#pragma unroll
    for (int c = 0; c < NCH; ++c) p |= ((unsigned)(groups[c] & 3)) << (2 * c);
    return p;
}

__device__ __forceinline__ void row_spec(const float* xs, const float* ts,
                                         float& accL, float& accG) {
    float lin[NCH], lg[NCH];
#pragma unroll
    for (int c = 0; c < NCH; ++c) {
        float xv = xs[c];
        lin[c] = fmaf(-xv, ts[c], fmaxf(xv, 0.0f));
        lg[c] = __log2f(1.0f + __expf(-fabsf(xv)));
    }
    // compile-time groups: g0={0,5,10} g1={1,2,8,12} g2={3,4,9,13} g3={6,7,11}
    float s1 = ts[1] + ts[2] + ts[8] + ts[12];
    float s2 = ts[3] + ts[4] + ts[9] + ts[13];
    float s3 = ts[6] + ts[7] + ts[11];

    float rL0 = lin[0] + lin[5] + lin[10],            rG0 = lg[0] + lg[5] + lg[10];
    float rL1 = lin[1] + lin[2] + lin[8] + lin[12],   rG1 = lg[1] + lg[2] + lg[8] + lg[12];
    float rL2 = lin[3] + lin[4] + lin[9] + lin[13],   rG2 = lg[3] + lg[4] + lg[9] + lg[13];
    float rL3 = lin[6] + lin[7] + lin[11],            rG3 = lg[6] + lg[7] + lg[11];

    accL += rL0;                        accG += rG0;
    accL += (s1 > 0.0f) ? rL1 : 0.0f;   accG += (s1 > 0.0f) ? rG1 : 0.0f;
    accL += (s2 > 0.0f) ? rL2 : 0.0f;   accG += (s2 > 0.0f) ? rG2 : 0.0f;
    accL += (s3 > 0.0f) ? rL3 : 0.0f;   accG += (s3 > 0.0f) ? rG3 : 0.0f;
}

__device__ __forceinline__ void row_gen(const float* xs, const float* ts,
                                        unsigned pack, float& accL, float& accG) {
    unsigned gb = 0u;
#pragma unroll
    for (int c = 0; c < NCH; ++c) {
        int gc = (pack >> (2 * c)) & 3;
        gb |= (ts[c] > 0.0f) ? (1u << gc) : 0u;
    }
#pragma unroll
    for (int c = 0; c < NCH; ++c) {
        int gc = (pack >> (2 * c)) & 3;
        float xv = xs[c];
        float lin = fmaf(-xv, ts[c], fmaxf(xv, 0.0f));
        float lg = __log2f(1.0f + __expf(-fabsf(xv)));
        bool keep = (gc == 0) || ((gb >> gc) & 1u);
        accL += keep ? lin : 0.0f;
        accG += keep ? lg : 0.0f;
    }
}

__device__ __forceinline__ void compute_pair(const float4* xv, const float4* tv,
                                             bool spec, unsigned pack,
                                             float& accL, float& accG) {
    float xs[2 * NCH], ts[2 * NCH];
#pragma unroll
    for (int j = 0; j < 7; ++j) {
        xs[4 * j + 0] = xv[j].x; xs[4 * j + 1] = xv[j].y;
        xs[4 * j + 2] = xv[j].z; xs[4 * j + 3] = xv[j].w;
        ts[4 * j + 0] = tv[j].x; ts[4 * j + 1] = tv[j].y;
        ts[4 * j + 2] = tv[j].z; ts[4 * j + 3] = tv[j].w;
    }
    if (spec) {
        row_spec(xs, ts, accL, accG);
        row_spec(xs + NCH, ts + NCH, accL, accG);
    } else {
        row_gen(xs, ts, pack, accL, accG);
        row_gen(xs + NCH, ts + NCH, pack, accL, accG);
    }
}

#define LOADP(XR, TRR, pp) do {                                        \
    const float4* xp_ = (const float4*)(x + (size_t)(pp) * (2 * NCH)); \
    const float4* tp_ = (const float4*)(t + (size_t)(pp) * (2 * NCH)); \
    _Pragma("unroll")                                                  \
    for (int j_ = 0; j_ < 7; ++j_) { XR[j_] = xp_[j_]; TRR[j_] = tp_[j_]; } \
} while (0)

__global__ __launch_bounds__(BT, 2) void bce_partial(
    const float* __restrict__ x, const float* __restrict__ t,
    const int* __restrict__ groups, float* __restrict__ partial,
    int rows, int iters)
{
    const unsigned pack = make_pack(groups);
    const bool spec = (pack == EXPECTED_PACK);
    const int pairs = rows >> 1;
    const int stride = gridDim.x * BT;

    float accL = 0.0f, accG = 0.0f;

    // Software pipeline: A/B register double-buffer, statically named (no
    // runtime indexing -> stays in VGPRs). Prefetch iter k+1 while computing k.
    float4 xa[7], ta[7], xb[7], tb[7];
    int p = blockIdx.x * BT + threadIdx.x;
    if (p < pairs) LOADP(xa, ta, p);

    for (int it = 0; it < iters; it += 2) {
        const int p1 = p + stride;
        if ((it + 1) < iters && p1 < pairs) LOADP(xb, tb, p1);
        if (p < pairs) compute_pair(xa, ta, spec, pack, accL, accG);

        const int p2 = p1 + stride;
        if ((it + 2) < iters && p2 < pairs) LOADP(xa, ta, p2);
        if ((it + 1) < iters && p1 < pairs) compute_pair(xb, tb, spec, pack, accL, accG);

        p = p2;
    }

    // Odd-row tail (rows=2e6 -> not taken; kept for generality).
    if ((rows & 1) && blockIdx.x == 0 && threadIdx.x == 0) {
        const size_t base = (size_t)(rows - 1) * NCH;
        float xs[NCH], ts[NCH];
#pragma unroll
        for (int c = 0; c < NCH; ++c) { xs[c] = x[base + c]; ts[c] = t[base + c]; }
        row_gen(xs, ts, pack, accL, accG);
    }

    float acc = fmaf(LN2F, accG, accL);

#pragma unroll
    for (int off = 32; off > 0; off >>= 1) acc += __shfl_xor(acc, off);

    __shared__ float wsum[BT / 64];
    const int lane = threadIdx.x & 63;
    const int wid = threadIdx.x >> 6;
    if (lane == 0) wsum[wid] = acc;
    __syncthreads();
    if (threadIdx.x == 0)
        partial[blockIdx.x] = wsum[0] + wsum[1] + wsum[2] + wsum[3];
}

__global__ __launch_bounds__(256) void finalize(
    const float* __restrict__ partial, int n, float* __restrict__ out, double inv_count)
{
    double s = 0.0;
    for (int i = threadIdx.x; i < n; i += 256) s += (double)partial[i];

    __shared__ double sd[256];
    sd[threadIdx.x] = s;
    __syncthreads();
#pragma unroll
    for (int step = 128; step > 0; step >>= 1) {
        if (threadIdx.x < step) sd[threadIdx.x] += sd[threadIdx.x + step];
        __syncthreads();
    }
    if (threadIdx.x == 0) out[0] = (float)(sd[0] * inv_count);
}

extern "C" void kernel_launch(void* const* d_in, const int* in_sizes, int n_in,
                              void* d_out, int out_size, void* d_ws, size_t ws_size,
                              hipStream_t stream) {
    const float* x = (const float*)d_in[0];
    const float* t = (const float*)d_in[1];
    const int* groups = (const int*)d_in[2];
    float* out = (float*)d_out;
    float* partial = (float*)d_ws;

    const int total = in_sizes[0];
    const int rows = total / NCH;
    const int pairs = rows >> 1;

    int blocks = NBLOCKS;                                   // persistent: 2 blocks/CU, fully resident
    const int maxb = (pairs + BT - 1) / BT;
    if (blocks > maxb) blocks = maxb;
    if ((size_t)blocks * sizeof(float) > ws_size)
        blocks = (int)(ws_size / sizeof(float));
    if (blocks < 1) blocks = 1;
    const int iters = (pairs + blocks * BT - 1) / (blocks * BT);

    bce_partial<<<blocks, BT, 0, stream>>>(x, t, groups, partial, rows, iters);

    const double inv_count = 1.0 / ((double)rows * (double)NCH);
    finalize<<<1, 256, 0, stream>>>(partial, blocks, out, inv_count);
}